// Round 4
// baseline (518.017 us; speedup 1.0000x reference)
//
#include <hip/hip_runtime.h>
#include <stdint.h>
#include <stddef.h>

#define IN_F 4096
#define OUT_F 4096
#define M_TOT 8192

// fused-fallback tile
#define BM 128
#define BN 128
#define BK 64

// main GEMM tile
#define BM2 256
#define BN2 256
#define BK2 64
#define NT2 (IN_F / BK2)   // 64 K-tiles

typedef __attribute__((ext_vector_type(8))) short short8;     // 8 x bf16 (4 VGPRs) MFMA A/B frag
typedef __attribute__((ext_vector_type(4))) float f32x4;      // MFMA C/D frag
typedef __attribute__((ext_vector_type(4))) float float4v;
typedef __attribute__((ext_vector_type(4))) unsigned short u16x4;
typedef __attribute__((ext_vector_type(8))) unsigned short u16x8;
typedef unsigned short u16;

// FP4 codebook (matches reference FP4_CODEBOOK exactly)
__constant__ float c_lut[16] = {
  0.0f, 0.0052f, 0.6667f, 1.0f, 0.3333f, 0.5f, 0.1667f, 0.25f,
  0.0f, -0.0052f, -0.6667f, -1.0f, -0.3333f, -0.5f, -0.1667f, -0.25f
};

// fp32 -> bf16 round-to-nearest-even
__device__ __forceinline__ u16 f2bf(float f) {
  unsigned int x = __float_as_uint(f);
  x += 0x7fffu + ((x >> 16) & 1u);
  return (u16)(x >> 16);
}

// async global->LDS, 16B per lane. LDS dest is wave-uniform base + lane*16.
__device__ __forceinline__ void gload_lds16(const u16* g, u16* lds) {
  __builtin_amdgcn_global_load_lds(
      (const __attribute__((address_space(1))) unsigned int*)g,
      (__attribute__((address_space(3))) unsigned int*)lds, 16, 0, 0);
}

// raw barrier; counted waits handle data deps (no full drain in steady state).
#define BARRIER() do { asm volatile("" ::: "memory"); \
                       __builtin_amdgcn_s_barrier();  \
                       asm volatile("" ::: "memory"); } while (0)
// counted lgkm wait + scheduler pin (rule #18: stops MFMA hoisting past the wait)
#define LGW(n) do { asm volatile("s_waitcnt lgkmcnt(" #n ")" ::: "memory"); \
                    __builtin_amdgcn_sched_barrier(0); } while (0)
#define VMW(n) asm volatile("s_waitcnt vmcnt(" #n ")" ::: "memory")

// ---------------- merged prep: W dequant (blocks 0..511) + x convert ----------------
__global__ __launch_bounds__(256) void k_prep(const float* __restrict__ x,
                                              u16* __restrict__ a,
                                              const int* __restrict__ wp,
                                              const float* __restrict__ scale,
                                              u16* __restrict__ b) {
  if (blockIdx.x < 512) {
    __shared__ float lut[16];
    if (threadIdx.x < 16) lut[threadIdx.x] = c_lut[threadIdx.x];
    __syncthreads();
    const int ng = (OUT_F * IN_F / 2) / 4;  // int4 groups
    const int stride = 512 * 256;
    for (int t = blockIdx.x * 256 + threadIdx.x; t < ng; t += stride) {
      int4 p = ((const int4*)wp)[t];
      float s = scale[t >> 3];
      int by[4] = {p.x, p.y, p.z, p.w};
      u16x8 o;
#pragma unroll
      for (int q = 0; q < 4; ++q) {
        o[2 * q]     = f2bf(lut[(by[q] >> 4) & 15] * s);
        o[2 * q + 1] = f2bf(lut[by[q] & 15] * s);
      }
      ((u16x8*)b)[t] = o;
    }
  } else {
    const int n8 = (M_TOT * IN_F) / 8;
    const int stride = 4096 * 256;
    for (int t = (blockIdx.x - 512) * 256 + threadIdx.x; t < n8; t += stride) {
      float4v f0 = ((const float4v*)x)[2 * t];
      float4v f1 = ((const float4v*)x)[2 * t + 1];
      u16x8 o;
      o[0] = f2bf(f0.x); o[1] = f2bf(f0.y); o[2] = f2bf(f0.z); o[3] = f2bf(f0.w);
      o[4] = f2bf(f1.x); o[5] = f2bf(f1.y); o[6] = f2bf(f1.z); o[7] = f2bf(f1.w);
      ((u16x8*)a)[t] = o;
    }
  }
}

// ===================== 256x256 full-flight pipelined GEMM =====================
// C = A(bf16, MxK) * B(bf16, NxK)^T + bias. 512 thr / 8 waves (2M x 4N),
// per-wave output 128x64 = acc[8][4] 16x16x32 frags. Quadrant order:
//   P1:(aC,b0) P2:(aC,b1) P3:(aN,b0) P4:(aN,b1)
// chosen so EVERY operand register set dies >=1 phase before its refill
// (register-neutral: operands stay at 96 VGPR; acc 128 AGPR; 2 waves/SIMD).
//
// Reads (each gets a FULL MFMA-cluster flight between issue and drain):
//   P1-top: rd b1_t(4)      -> drained P2's LGW(8)   (flies through P1 MFMA)
//   P2-top: rd aN_t(8)      -> drained P3's LGW(8)   (flies through P2)
//   P3-top: rd aC_{t+1}(8)  -> drained P1' LGW(4)    (flies through P3+P4)
//   P4-top: rd b0_{t+1}(4)  -> drained P1' LGW(4)    (flies through P4)
// LGW counts: P1: queue[aC 8, b0 4, b1 4] -> LGW(4); P2: [b1 4, aN 8] ->
// LGW(8); P3: [aN 8, aC' 8] -> LGW(8) (LGW(0) last tile); P4: none.
//
// Staging: uniform 3-phase lead, 2 gloads/phase-top:
//   P1: B0_{t+1}  P2: B1_{t+1}  P3: A1_{t+1}  P4: A0_{t+2}
// Pre-barrier VMW(4) at every phase drains exactly the 2-phase-old pair that
// the NEXT phase-top ds_reads (1240cyc flight > ~900cyc HBM -> no stall), and
// publishes it across waves via the barrier. Tail (t >= NT2-3): VMW(0).
// LDS chunk-XOR swizzle: LDS 16B-chunk p of row r holds GLOBAL chunk p^(r&7).

__device__ __forceinline__ void st_b(const u16* __restrict__ B, u16* dst,
                                     int nBase, int kt, int h, int k,
                                     int wave, int srow, int scol) {
  const int r0 = 64 * (wave >> 1) + 32 * h + 16 * k + 8 * (wave & 1);
  gload_lds16(B + (size_t)(nBase + r0 + srow) * IN_F + kt + scol, dst + r0 * BK2);
}
__device__ __forceinline__ void st_a(const u16* __restrict__ A, u16* dst,
                                     int mBase, int kt, int h, int k,
                                     int wave, int srow, int scol) {
  const int r0 = 128 * (wave >> 2) + 64 * h + 32 * k + 8 * (wave & 3);
  gload_lds16(A + (size_t)(mBase + r0 + srow) * IN_F + kt + scol, dst + r0 * BK2);
}

__device__ __forceinline__ void rd_b(short8 d[2][2], const u16* Bs_c, int bBase,
                                     int co0, int co1, int h) {
#pragma unroll
  for (int jj = 0; jj < 2; ++jj) {
    const int ro = bBase + (h * 2 + jj) * (16 * BK2);
    d[jj][0] = *(const short8*)&Bs_c[ro + co0];
    d[jj][1] = *(const short8*)&Bs_c[ro + co1];
  }
}
__device__ __forceinline__ void rd_a(short8 d[4][2], const u16* As_c, int aBase,
                                     int co0, int co1, int h) {
#pragma unroll
  for (int ii = 0; ii < 4; ++ii) {
    const int ro = aBase + (h * 4 + ii) * (16 * BK2);
    d[ii][0] = *(const short8*)&As_c[ro + co0];
    d[ii][1] = *(const short8*)&As_c[ro + co1];
  }
}
__device__ __forceinline__ void mma8(f32x4 acc[8][4], const short8 a[4][2],
                                     const short8 b[2][2], int i0, int j0) {
#pragma unroll
  for (int k2 = 0; k2 < 2; ++k2)
#pragma unroll
    for (int ii = 0; ii < 4; ++ii)
#pragma unroll
      for (int jj = 0; jj < 2; ++jj)
        acc[i0 + ii][j0 + jj] = __builtin_amdgcn_mfma_f32_16x16x32_bf16(
            a[ii][k2], b[jj][k2], acc[i0 + ii][j0 + jj], 0, 0, 0);
}

__global__ __launch_bounds__(512, 2) void k_gemm256(const u16* __restrict__ A,
                                                    const u16* __restrict__ B,
                                                    const float* __restrict__ bias,
                                                    float* __restrict__ C) {
  __shared__ u16 As[2][BM2 * BK2];   // 2 x 32 KiB
  __shared__ u16 Bs[2][BN2 * BK2];   // 2 x 32 KiB

  const int tid  = threadIdx.x;
  const int lane = tid & 63;
  const int wave = tid >> 6;

  // XCD-aware tile swizzle: 8x8 tile square per XCD (grid 32x16 = 512, %8==0)
  const int bid   = blockIdx.x;
  const int xcd   = bid & 7;
  const int kk    = bid >> 3;
  const int tileM = (xcd >> 1) * 8 + (kk >> 3);
  const int tileN = (xcd & 1) * 8 + (kk & 7);
  const int mBase = tileM * BM2;
  const int nBase = tileN * BN2;

  const int wm = (wave >> 2) * 128;
  const int wn = (wave & 3) * 64;

  // staging lane decomposition (8 rows x 64 cols per gload, XOR-swizzled source)
  const int srow = lane >> 3;
  const int scol = ((lane & 7) ^ srow) * 8;

  // MFMA operand addressing
  const int frow = lane & 15;
  const int fx   = frow & 7;
  const int cq   = lane >> 4;
  const int co0  = ((cq ^ fx) << 3);
  const int co1  = (((4 + cq) ^ fx) << 3);
  const int aBase = (wm + frow) * BK2;
  const int bBase = (wn + frow) * BK2;

  f32x4 acc[8][4] = {};
  short8 aC[4][2], aN[4][2], b0[2][2], b1[2][2];

  // ---- prologue: tile0 {A0,B0,B1,A1} (8 rounds) + A0_1 (2 rounds) ----
  st_a(A, As[0], mBase, 0, 0, 0, wave, srow, scol);
  st_a(A, As[0], mBase, 0, 0, 1, wave, srow, scol);
  st_b(B, Bs[0], nBase, 0, 0, 0, wave, srow, scol);
  st_b(B, Bs[0], nBase, 0, 0, 1, wave, srow, scol);
  st_b(B, Bs[0], nBase, 0, 1, 0, wave, srow, scol);
  st_b(B, Bs[0], nBase, 0, 1, 1, wave, srow, scol);
  st_a(A, As[0], mBase, 0, 1, 0, wave, srow, scol);
  st_a(A, As[0], mBase, 0, 1, 1, wave, srow, scol);
  st_a(A, As[1], mBase, BK2, 0, 0, wave, srow, scol);
  st_a(A, As[1], mBase, BK2, 0, 1, wave, srow, scol);
  VMW(2);            // tile0's 8 rounds landed; A0_1 pair stays in flight
  BARRIER();
  rd_a(aC, As[0], aBase, co0, co1, 0);   // lgkm queue: [aC 8]
  rd_b(b0, Bs[0], bBase, co0, co1, 0);   // lgkm queue: [aC 8, b0 4]

  for (int t = 0; t < NT2; ++t) {
    const int c = t & 1;
    u16* AsC = As[c];
    u16* BsC = Bs[c];
    u16* AsO = As[c ^ 1];
    u16* BsO = Bs[c ^ 1];
    const int kt1 = (t + 1) * BK2;
    const int kt2 = (t + 2) * BK2;

    // ---------- P1: MFMA aC x b0 ----------
    rd_b(b1, BsC, bBase, co0, co1, 1);             // b1_t, flies through P1
    if (t + 1 < NT2) {
      st_b(B, BsO, nBase, kt1, 0, 0, wave, srow, scol);   // B0_{t+1}
      st_b(B, BsO, nBase, kt1, 0, 1, wave, srow, scol);
    }
    if (t < NT2 - 3) { VMW(4); } else { VMW(0); }  // publish pair read next top
    BARRIER();
    LGW(4);                                        // drain aC_t + b0_t
    __builtin_amdgcn_s_setprio(1);
    mma8(acc, aC, b0, 0, 0);
    __builtin_amdgcn_s_setprio(0);

    // ---------- P2: MFMA aC x b1 ----------
    rd_a(aN, AsC, aBase, co0, co1, 1);             // aN_t, flies through P2
    if (t + 1 < NT2) {
      st_b(B, BsO, nBase, kt1, 1, 0, wave, srow, scol);   // B1_{t+1}
      st_b(B, BsO, nBase, kt1, 1, 1, wave, srow, scol);
    }
    if (t < NT2 - 3) { VMW(4); } else { VMW(0); }
    BARRIER();
    LGW(8);                                        // drain b1_t
    __builtin_amdgcn_s_setprio(1);
    mma8(acc, aC, b1, 0, 2);
    __builtin_amdgcn_s_setprio(0);

    // ---------- P3: MFMA aN x b0 ----------
    if (t + 1 < NT2) rd_a(aC, AsO, aBase, co0, co1, 0);   // aC_{t+1} refill
    if (t + 1 < NT2) {
      st_a(A, AsO, mBase, kt1, 1, 0, wave, srow, scol);   // A1_{t+1}
      st_a(A, AsO, mBase, kt1, 1, 1, wave, srow, scol);
    }
    if (t < NT2 - 3) { VMW(4); } else { VMW(0); }
    BARRIER();
    if (t + 1 < NT2) { LGW(8); } else { LGW(0); }  // drain aN_t
    __builtin_amdgcn_s_setprio(1);
    mma8(acc, aN, b0, 4, 0);
    __builtin_amdgcn_s_setprio(0);

    // ---------- P4: MFMA aN x b1 ----------
    if (t + 1 < NT2) rd_b(b0, BsO, bBase, co0, co1, 0);   // b0_{t+1} refill
    if (t + 2 < NT2) {
      st_a(A, AsC, mBase, kt2, 0, 0, wave, srow, scol);   // A0_{t+2} -> cur buf
      st_a(A, AsC, mBase, kt2, 0, 1, wave, srow, scol);
    }
    if (t < NT2 - 3) { VMW(4); } else { VMW(0); }
    BARRIER();
    __builtin_amdgcn_sched_barrier(0);             // deps already drained (P2/P3)
    __builtin_amdgcn_s_setprio(1);
    mma8(acc, aN, b1, 4, 2);
    __builtin_amdgcn_s_setprio(0);
  }

  // epilogue: C/D layout col = lane&15, row = (lane>>4)*4 + reg   [m89-verified]
  const int ccol = lane & 15;
  const int crow = (lane >> 4) * 4;
#pragma unroll
  for (int j = 0; j < 4; ++j) {
    const int col = nBase + wn + j * 16 + ccol;
    const float bv = bias[col];
#pragma unroll
    for (int i = 0; i < 8; ++i) {
      const size_t rb = (size_t)(mBase + wm + i * 16 + crow) * OUT_F + col;
#pragma unroll
      for (int tt = 0; tt < 4; ++tt)
        C[rb + (size_t)tt * OUT_F] = acc[i][j][tt] + bv;
    }
  }
}

// -------- fallback: fully fused (no workspace), register-staged conversion --------
__global__ __launch_bounds__(256) void k_gemm_fused(const float* __restrict__ X,
                                                    const int* __restrict__ WP,
                                                    const float* __restrict__ scale,
                                                    const float* __restrict__ bias,
                                                    float* __restrict__ C) {
  __shared__ u16 As[BM * BK];
  __shared__ u16 Bs[BN * BK];
  __shared__ float lut[16];
  const int tid = threadIdx.x;
  if (tid < 16) lut[tid] = c_lut[tid];
  const int lane = tid & 63;
  const int wave = tid >> 6;
  const int mBase = blockIdx.y * BM;
  const int nBase = blockIdx.x * BN;
  const int wm = (wave >> 1) * 64;
  const int wn = (wave & 1) * 64;
  const int frow = lane & 15;
  const int fx   = lane & 7;
  const int cq   = lane >> 4;
  f32x4 acc[4][4] = {};
  __syncthreads();  // lut ready

  for (int kt = 0; kt < IN_F; kt += BK) {
#pragma unroll
    for (int i = 0; i < 8; ++i) {
      const int g = tid + i * 256;
      const int r = g >> 4, c = (g & 15) * 4;
      float4v f = *(const float4v*)&X[(size_t)(mBase + r) * IN_F + kt + c];
      u16x4 o;
      o.x = f2bf(f.x); o.y = f2bf(f.y); o.z = f2bf(f.z); o.w = f2bf(f.w);
      *(u16x4*)&As[r * BK + ((((c >> 3) ^ (r & 7)) << 3) | (c & 7))] = o;
    }
#pragma unroll
    for (int i = 0; i < 4; ++i) {
      const int g = tid + i * 256;
      const int r = g >> 3, c4 = (g & 7) * 4;
      int4 p = *(const int4*)&WP[(size_t)(nBase + r) * (IN_F / 2) + (kt >> 1) + c4];
      const float s = scale[(nBase + r) * 64 + (kt >> 6)];
      int by[4] = {p.x, p.y, p.z, p.w};
      u16x8 o;
#pragma unroll
      for (int q = 0; q < 4; ++q) {
        o[2 * q]     = f2bf(lut[(by[q] >> 4) & 15] * s);
        o[2 * q + 1] = f2bf(lut[by[q] & 15] * s);
      }
      *(u16x8*)&Bs[r * BK + (((g & 7) ^ (r & 7)) << 3)] = o;
    }
    __syncthreads();
#pragma unroll
    for (int ks = 0; ks < BK; ks += 32) {
      const int co = (((ks >> 3) + cq) ^ fx) << 3;
      short8 a[4], b[4];
#pragma unroll
      for (int i = 0; i < 4; ++i)
        a[i] = *(const short8*)&As[(wm + i * 16 + frow) * BK + co];
#pragma unroll
      for (int j = 0; j < 4; ++j)
        b[j] = *(const short8*)&Bs[(wn + j * 16 + frow) * BK + co];
#pragma unroll
      for (int i = 0; i < 4; ++i)
#pragma unroll
        for (int j = 0; j < 4; ++j)
          acc[i][j] = __builtin_amdgcn_mfma_f32_16x16x32_bf16(a[i], b[j], acc[i][j], 0, 0, 0);
    }
    __syncthreads();
  }

  const int ccol = lane & 15;
  const int crow = (lane >> 4) * 4;
#pragma unroll
  for (int j = 0; j < 4; ++j) {
    const int col = nBase + wn + j * 16 + ccol;
    const float bv = bias[col];
#pragma unroll
    for (int i = 0; i < 4; ++i) {
      const size_t rb = (size_t)(mBase + wm + i * 16 + crow) * OUT_F + col;
#pragma unroll
      for (int t = 0; t < 4; ++t)
        C[rb + (size_t)t * OUT_F] = acc[i][j][t] + bv;
    }
  }
}

extern "C" void kernel_launch(void* const* d_in, const int* in_sizes, int n_in,
                              void* d_out, int out_size, void* d_ws, size_t ws_size,
                              hipStream_t stream) {
  const float* x  = (const float*)d_in[0];
  const int*   wp = (const int*)d_in[1];
  const float* sc = (const float*)d_in[2];
  const float* bi = (const float*)d_in[3];
  float* out = (float*)d_out;

  const size_t bBytes = (size_t)OUT_F * IN_F * 2;   // 33.5 MB bf16 W
  const size_t aBytes = (size_t)M_TOT * IN_F * 2;   // 67 MB bf16 x

  if (ws_size >= aBytes + bBytes) {
    u16* B = (u16*)d_ws;
    u16* A = (u16*)((char*)d_ws + bBytes);
    k_prep<<<4608, 256, 0, stream>>>(x, A, wp, sc, B);
    k_gemm256<<<(M_TOT / BM2) * (OUT_F / BN2), 512, 0, stream>>>(A, B, bi, out);
  } else {
    dim3 grid(OUT_F / BN, M_TOT / BM);
    k_gemm_fused<<<grid, 256, 0, stream>>>(x, wp, sc, bi, out);
  }
}